// Round 3
// baseline (92.659 us; speedup 1.0000x reference)
//
#include <hip/hip_runtime.h>
#include <math.h>

typedef float v4f __attribute__((ext_vector_type(4)));

#define TPB 256   // threads per block
#define IPT 8     // "self" rows per thread (registers)
#define JS  128   // j-slices per direction (split over the other cloud)
#define TS  512   // LDS tile in points (even) -> 8 KB LDS

// ---------------------------------------------------------------------------
// 2-dispatch structure (was 3): the separate setup kernel and the atomicMin
// pack-init are both gone.
//  - pairs_kernel transforms on the fly: self rows inline (backward dir),
//    other-chunk into an LDS tile once per block (forward dir). No staged
//    clouds in global memory.
//  - split-K merge via a race-free per-(slice,row) partial key array
//    part[jb][i] (coalesced writes, no init needed, no atomics);
//    finalize min-reduces the JS keys per row.
//  - key = sortable(trunc_score_with_embedded_local_j) << 32 | global_j;
//    u64 min => smallest truncated score, ties -> smallest global j.
//    finalize recomputes the EXACT distance from the winning index.
// ---------------------------------------------------------------------------

__device__ __forceinline__ unsigned int sortable(float f) {
  unsigned int u = __float_as_uint(f);
  return u ^ ((unsigned int)((int)u >> 31) | 0x80000000u);
}

struct Xform {
  float t0, t1, t2, t3, t4, t5, t6, t7, t8, t9, t10, t11;
};

__device__ __forceinline__ Xform load_xform(const float* __restrict__ T) {
  Xform X = {T[0], T[1], T[2], T[3], T[4],  T[5],
             T[6], T[7], T[8], T[9], T[10], T[11]};
  return X;
}

__device__ __forceinline__ void apply_xform(const Xform& X, float& x, float& y,
                                            float& z) {
  float tx = X.t0 * x + X.t1 * y + X.t2 * z + X.t3;
  float ty = X.t4 * x + X.t5 * y + X.t6 * z + X.t7;
  float tz = X.t8 * x + X.t9 * y + X.t10 * z + X.t11;
  x = tx; y = ty; z = tz;
}

// ---------------------------------------------------------------------------
// Kernel 1: fused transform + bidirectional split-K argmin over
// score_j = |q_j|^2 - 2 p.q_j (equal-argmin to squared distance).
// Inner loop per 2 j's per row: 6 v_fma + 2 v_and_or + 2 v_min, branchless.
// ---------------------------------------------------------------------------
__global__ __launch_bounds__(TPB, 4) void pairs_kernel(
    const float* __restrict__ ref, const float* __restrict__ src,
    const float* __restrict__ T,
    unsigned long long* __restrict__ partF,
    unsigned long long* __restrict__ partB,
    float* __restrict__ out, int N, int M, int nbF) {
  __shared__ __align__(16) float tile[TS * 4];
  const int b0 = blockIdx.x;
  if (b0 == 0 && threadIdx.x == 0) out[0] = 0.0f;  // before finalize dispatch

  const Xform X = load_xform(T);

  const bool fwd = (b0 < nbF);
  const int b = fwd ? b0 : b0 - nbF;
  const float* selfP  = fwd ? ref : src;   // backward self needs transform
  const float* otherP = fwd ? src : ref;   // forward other needs transform
  unsigned long long* part = fwd ? partF : partB;
  const int selfN  = fwd ? N : M;
  const int otherN = fwd ? M : N;

  const int ib = b / JS, jb = b % JS;
  const int i0 = ib * (TPB * IPT) + threadIdx.x;

  float ax[IPT], ay[IPT], az[IPT], m0[IPT], m1[IPT];
#pragma unroll
  for (int k = 0; k < IPT; k++) {
    int i = i0 + k * TPB;
    int ic = (i < selfN) ? i : (selfN - 1);  // clamp; guarded at write time
    float x = selfP[3 * ic], y = selfP[3 * ic + 1], z = selfP[3 * ic + 2];
    if (!fwd) apply_xform(X, x, y, z);
    ax[k] = -2.0f * x; ay[k] = -2.0f * y; az[k] = -2.0f * z;
    m0[k] = 1e30f; m1[k] = 1e30f;
  }

  int chunk = (otherN + JS - 1) / JS;
  chunk = (chunk + 1) & ~1;  // even
  const int j0 = jb * chunk;
  const int jcount = min(chunk, otherN - j0);  // may be <= 0

  // low ceil(log2(chunk)) mantissa bits of the score carry the local j
  const int lowbits = 32 - __clz((chunk > 2 ? chunk : 2) - 1);
  const unsigned keep = ~((1u << lowbits) - 1u);

  for (int jt = 0; jt < jcount; jt += TS) {
    const int tc = min(TS, jcount - jt);
    const int tce = (tc + 1) & ~1;  // even; pad slot gets sentinel
    // stage (+ transform) the other-chunk tile into LDS as {x,y,z,w}
    for (int t = threadIdx.x; t < tce; t += TPB) {
      int j = j0 + jt + t;
      float x = 0.f, y = 0.f, z = 0.f, w = 1e30f;
      if (j < otherN) {
        x = otherP[3 * j]; y = otherP[3 * j + 1]; z = otherP[3 * j + 2];
        if (fwd) apply_xform(X, x, y, z);
        w = x * x + y * y + z * z;
      }
      tile[4 * t] = x; tile[4 * t + 1] = y;
      tile[4 * t + 2] = z; tile[4 * t + 3] = w;
    }
    __syncthreads();
#pragma unroll 4
    for (int jj = 0; jj < tce; jj += 2) {
      v4f A = *(const v4f*)&tile[4 * jj];      // {x,y,z,w} of j   (broadcast)
      v4f B = *(const v4f*)&tile[4 * jj + 4];  // {x,y,z,w} of j+1
      const unsigned ej0 = (unsigned)(jt + jj);
      const unsigned ej1 = (unsigned)(jt + jj + 1);
#pragma unroll
      for (int k = 0; k < IPT; k++) {
        float u0 = __builtin_fmaf(ax[k], A.x, A.w);
        u0 = __builtin_fmaf(ay[k], A.y, u0);
        u0 = __builtin_fmaf(az[k], A.z, u0);
        float u1 = __builtin_fmaf(ax[k], B.x, B.w);
        u1 = __builtin_fmaf(ay[k], B.y, u1);
        u1 = __builtin_fmaf(az[k], B.z, u1);
        float e0 = __uint_as_float((__float_as_uint(u0) & keep) | ej0);
        float e1 = __uint_as_float((__float_as_uint(u1) & keep) | ej1);
        m0[k] = fminf(m0[k], e0);
        m1[k] = fminf(m1[k], e1);
      }
    }
    __syncthreads();  // tile reuse guard (no-op cost on single-tile chunks)
  }

#pragma unroll
  for (int k = 0; k < IPT; k++) {
    int i = i0 + k * TPB;
    if (i < selfN) {
      unsigned long long key;
      if (jcount > 0) {
        float mf = fminf(m0[k], m1[k]);
        unsigned mb = __float_as_uint(mf);
        unsigned jloc = mb & ~keep;
        key = ((unsigned long long)sortable(mf) << 32) |
              (unsigned)(j0 + (int)jloc);
      } else {
        key = ~0ull;  // empty slice: loses to any real key
      }
      part[(size_t)jb * selfN + i] = key;  // race-free, coalesced, no init
    }
  }
}

// ---------------------------------------------------------------------------
// Kernel 2: per row min-reduce the JS slice keys (coalesced: each step a
// wave reads 64 consecutive u64), decode index, recompute exact distance
// (transform recomputed inline), loss term, block reduce, one atomicAdd.
// ---------------------------------------------------------------------------
__global__ __launch_bounds__(256) void finalize_kernel(
    const unsigned long long* __restrict__ partF,
    const unsigned long long* __restrict__ partB,
    const float* __restrict__ ref, const float* __restrict__ src,
    const float* __restrict__ T,
    const float* __restrict__ ref_sigma, const float* __restrict__ src_sigma,
    float* __restrict__ out, int N, int M) {
  int gid = blockIdx.x * blockDim.x + threadIdx.x;
  const Xform X = load_xform(T);
  float term = 0.f;
  if (gid < N) {
    unsigned long long ma = ~0ull, mb = ~0ull;
#pragma unroll 8
    for (int s = 0; s < JS; s += 2) {
      unsigned long long k0 = partF[(size_t)s * N + gid];
      unsigned long long k1 = partF[(size_t)(s + 1) * N + gid];
      ma = (k0 < ma) ? k0 : ma;
      mb = (k1 < mb) ? k1 : mb;
    }
    unsigned long long m = (ma < mb) ? ma : mb;
    int idx = (int)(m & 0xffffffffu);
    float x = src[3 * idx], y = src[3 * idx + 1], z = src[3 * idx + 2];
    apply_xform(X, x, y, z);
    float dx = ref[3 * gid] - x, dy = ref[3 * gid + 1] - y,
          dz = ref[3 * gid + 2] - z;
    float d = sqrtf(dx * dx + dy * dy + dz * dz);
    float sigma = 0.5f * (ref_sigma[gid] + src_sigma[idx]);
    term = (logf(sigma) + d / sigma) * (1.0f / (float)N);
  } else if (gid < N + M) {
    int j = gid - N;
    unsigned long long ma = ~0ull, mb = ~0ull;
#pragma unroll 8
    for (int s = 0; s < JS; s += 2) {
      unsigned long long k0 = partB[(size_t)s * M + j];
      unsigned long long k1 = partB[(size_t)(s + 1) * M + j];
      ma = (k0 < ma) ? k0 : ma;
      mb = (k1 < mb) ? k1 : mb;
    }
    unsigned long long m = (ma < mb) ? ma : mb;
    int idx = (int)(m & 0xffffffffu);
    float x = src[3 * j], y = src[3 * j + 1], z = src[3 * j + 2];
    apply_xform(X, x, y, z);
    float dx = x - ref[3 * idx], dy = y - ref[3 * idx + 1],
          dz = z - ref[3 * idx + 2];
    float d = sqrtf(dx * dx + dy * dy + dz * dz);
    float sigma = 0.5f * (src_sigma[j] + ref_sigma[idx]);
    term = (logf(sigma) + d / sigma) * (1.0f / (float)M);
  }
#pragma unroll
  for (int o = 32; o > 0; o >>= 1) term += __shfl_down(term, o, 64);
  __shared__ float wsum[4];
  const int lane = threadIdx.x & 63, wid = threadIdx.x >> 6;
  if (lane == 0) wsum[wid] = term;
  __syncthreads();
  if (threadIdx.x == 0)
    atomicAdd(out, wsum[0] + wsum[1] + wsum[2] + wsum[3]);
}

extern "C" void kernel_launch(void* const* d_in, const int* in_sizes, int n_in,
                              void* d_out, int out_size, void* d_ws,
                              size_t ws_size, hipStream_t stream) {
  const float* ref_kpts  = (const float*)d_in[0];
  const float* src_kpts  = (const float*)d_in[1];
  const float* gt        = (const float*)d_in[2];
  const float* ref_sigma = (const float*)d_in[3];
  const float* src_sigma = (const float*)d_in[4];
  float* out = (float*)d_out;

  const int N = in_sizes[0] / 3;
  const int M = in_sizes[1] / 3;

  // workspace: just the two partial-key arrays (JS keys per row)
  unsigned long long* partF = (unsigned long long*)d_ws;
  unsigned long long* partB = partF + (size_t)JS * N;

  const int ibF = (N + TPB * IPT - 1) / (TPB * IPT);
  const int ibB = (M + TPB * IPT - 1) / (TPB * IPT);
  const int nbF = ibF * JS;
  const int nbB = ibB * JS;
  pairs_kernel<<<nbF + nbB, TPB, 0, stream>>>(ref_kpts, src_kpts, gt, partF,
                                              partB, out, N, M, nbF);

  finalize_kernel<<<(N + M + 255) / 256, 256, 0, stream>>>(
      partF, partB, ref_kpts, src_kpts, gt, ref_sigma, src_sigma, out, N, M);
}